// Round 18
// baseline (123.741 us; speedup 1.0000x reference)
//
#include <hip/hip_runtime.h>
#include <hip/hip_fp16.h>

typedef _Float16 f16;
typedef _Float16 f16x8 __attribute__((ext_vector_type(8)));
typedef float f32x4 __attribute__((ext_vector_type(4)));
typedef unsigned u32x4 __attribute__((ext_vector_type(4)));

#define AS1(p) ((const __attribute__((address_space(1))) void*)(p))
#define AS3(p) ((__attribute__((address_space(3))) void*)(p))

__device__ __forceinline__ void gload16(const void* g, void* l) {
  __builtin_amdgcn_global_load_lds(AS1(g), AS3(l), 16, 0, 0);
}

__device__ __forceinline__ float sgm(float x) {
  // sigmoid(16*x) = 1/(1+2^(-16*log2e*x))
  return __builtin_amdgcn_rcpf(1.0f + __builtin_amdgcn_exp2f(x * -23.083120654223414f));
}

// ---------------------------------------------------------------------------
// Tiled transpose + f32->f16 convert body: 64x64 tile.
// ---------------------------------------------------------------------------
__device__ __forceinline__ void tbody(const float* __restrict__ ip,
                                      f16* __restrict__ op,
                                      long in_rs, long out_rs) {
  __shared__ float t[64][68];
  int tid = threadIdx.x;
  {
    int c4 = (tid & 15) * 4, r0 = tid >> 4;
#pragma unroll
    for (int p = 0; p < 4; ++p) {
      int r = r0 + 16 * p;
      float4 v = *(const float4*)(ip + (long)r * in_rs + c4);
      t[c4 + 0][r] = v.x; t[c4 + 1][r] = v.y; t[c4 + 2][r] = v.z; t[c4 + 3][r] = v.w;
    }
  }
  __syncthreads();
  {
    int r4 = (tid & 15) * 4, c0 = tid >> 4;
#pragma unroll
    for (int p = 0; p < 4; ++p) {
      int c = c0 + 16 * p;
      float4 v = *(const float4*)(&t[c][r4]);
      union { f16 h[4]; unsigned long long u; } pk;
      pk.h[0] = (f16)v.x; pk.h[1] = (f16)v.y; pk.h[2] = (f16)v.z; pk.h[3] = (f16)v.w;
      *(unsigned long long*)(op + (long)c * out_rs + r4) = pk.u;
    }
  }
}

// All input transposes in one launch. Flat grid 1024 blocks.
__global__ __launch_bounds__(256) void tall(
    const float* __restrict__ qin, const float* __restrict__ kvin,
    const float* __restrict__ Wq, const float* __restrict__ Wk,
    const float* __restrict__ Wv, const float* __restrict__ Wz,
    f16* __restrict__ Xq, f16* __restrict__ Xkv,
    f16* __restrict__ Wqt, f16* __restrict__ Wkt, f16* __restrict__ Wvt,
    f16* __restrict__ Wzt) {
  int id = blockIdx.x;
  if (id < 512) {
    int x = id & 15, y = (id >> 4) & 3, z = id >> 6;
    const float* in = (z < 4) ? qin : kvin;
    f16* out = (z < 4) ? Xq : Xkv;
    long b = z & 3;
    tbody(in + b * 262144 + (long)(y * 64) * 1024 + x * 64,
          out + b * 262144 + (long)(x * 64) * 256 + y * 64, 1024, 256);
  } else if (id < 896) {
    int t = id - 512;
    int x = t & 31, y = (t >> 5) & 3, z = t >> 7;
    const float* in = (z == 0) ? Wq : (z == 1) ? Wk : Wv;
    f16* out = (z == 0) ? Wqt : (z == 1) ? Wkt : Wvt;
    tbody(in + (long)(y * 64) * 2048 + x * 64,
          out + (long)(x * 64) * 256 + y * 64, 2048, 256);
  } else {
    int t = id - 896;
    int x = t & 3, y = (t >> 2) & 3;
    long z = t >> 4;
    tbody(Wz + z * 256 + (long)(y * 64) * 2048 + x * 64,
          Wzt + z * 256 + (long)(x * 64) * 2048 + y * 64, 2048, 2048);
  }
}

// ---------------------------------------------------------------------------
// QKV projection, double-buffered staging. BM=BN=128, BK=64.  (r11-exact)
// z=0: Q -> Qh[b][h][s][fi]; z=1: K -> Kh; z=2: V -> Vt[b][h][fi][s]
// grid (32,16,3), 256 threads.
// ---------------------------------------------------------------------------
__global__ __launch_bounds__(256) void projk(
    const f16* __restrict__ Xq, const f16* __restrict__ Xkv,
    const f16* __restrict__ Wqt, const f16* __restrict__ Wkt, const f16* __restrict__ Wvt,
    f16* __restrict__ Qh, f16* __restrict__ Kh, f16* __restrict__ Vt) {
  __shared__ char sm[65536];
  int z = blockIdx.z;
  const f16* A = (z == 0) ? Xq : Xkv;
  const f16* B = (z == 0) ? Wqt : (z == 1) ? Wkt : Wvt;
  int m0 = blockIdx.x * 128, n0 = blockIdx.y * 128;
  int tid = threadIdx.x, wave = tid >> 6, lane = tid & 63;
  int wm = wave & 1, wn = wave >> 1;
  f32x4 acc[4][4];
#pragma unroll
  for (int i = 0; i < 4; ++i)
#pragma unroll
    for (int j = 0; j < 4; ++j) acc[i][j] = (f32x4){0.f, 0.f, 0.f, 0.f};

  auto PSTAGE = [&](int buf, int kt) {
    char* As = sm + buf * 32768;
    char* Bs = As + 16384;
    int k0 = kt * 64;
#pragma unroll
    for (int is = 0; is < 4; ++is) {
      int loff = is * 4096 + wave * 1024;
      int g = loff + lane * 16;
      int row = g >> 7, sl = (g >> 4) & 7;
      int sp = (sl ^ (row & 7)) * 8;
      gload16(A + (long)(m0 + row) * 256 + k0 + sp, As + loff);
      gload16(B + (long)(n0 + row) * 256 + k0 + sp, Bs + loff);
    }
  };

  PSTAGE(0, 0);
  __syncthreads();
  for (int kt = 0; kt < 4; ++kt) {
    int cur = kt & 1;
    if (kt < 3) PSTAGE(cur ^ 1, kt + 1);
    const char* As = sm + cur * 32768;
    const char* Bs = As + 16384;
#pragma unroll
    for (int t = 0; t < 2; ++t) {
      f16x8 af[4], bf[4];
#pragma unroll
      for (int mi = 0; mi < 4; ++mi) {
        int row = wm * 64 + mi * 16 + (lane & 15);
        int sl = (t * 4 + (lane >> 4)) ^ (row & 7);
        af[mi] = *(const f16x8*)(As + row * 128 + sl * 16);
      }
#pragma unroll
      for (int ni = 0; ni < 4; ++ni) {
        int row = wn * 64 + ni * 16 + (lane & 15);
        int sl = (t * 4 + (lane >> 4)) ^ (row & 7);
        bf[ni] = *(const f16x8*)(Bs + row * 128 + sl * 16);
      }
#pragma unroll
      for (int mi = 0; mi < 4; ++mi)
#pragma unroll
        for (int ni = 0; ni < 4; ++ni)
          acc[mi][ni] = __builtin_amdgcn_mfma_f32_16x16x32_f16(af[mi], bf[ni], acc[mi][ni], 0, 0, 0);
    }
    __syncthreads();
  }
#pragma unroll
  for (int mi = 0; mi < 4; ++mi)
#pragma unroll
    for (int ni = 0; ni < 4; ++ni) {
      int cc = wn * 64 + ni * 16 + (lane & 15);
      int rs0 = wm * 64 + mi * 16 + (lane >> 4) * 4;
      union { f16 h[4]; unsigned long long u; } pk;
#pragma unroll
      for (int r = 0; r < 4; ++r) pk.h[r] = (f16)acc[mi][ni][r];
      *(unsigned long long*)(sm + cc * 272 + rs0 * 2) = pk.u;
    }
  __syncthreads();
  if (z < 2) {
    f16* outp = (z == 0) ? Qh : Kh;
#pragma unroll
    for (int pass = 0; pass < 4; ++pass) {
      int item = pass * 256 + tid;
      int rs = item & 127, h = item >> 7;
      int m = m0 + rs, b = m >> 10, s = m & 1023;
      union { unsigned short u16[16]; uint4 q[2]; } pk;
#pragma unroll
      for (int u = 0; u < 16; ++u)
        pk.u16[u] = *(const unsigned short*)(sm + (h + 8 * u) * 272 + rs * 2);
      f16* dst = outp + ((long)(b * 8 + h) * 1024 + s) * 256 + (n0 >> 3);
      *(uint4*)dst = pk.q[0];
      *(uint4*)(dst + 8) = pk.q[1];
    }
  } else {
    int cc = tid >> 1, half = tid & 1;
    int c = n0 + cc, h = c & 7, fi = c >> 3;
    int m = m0 + half * 64;
    int b = m >> 10, s0 = m & 1023;
    uint4 q[8];
#pragma unroll
    for (int j = 0; j < 8; ++j)
      q[j] = *(const uint4*)(sm + cc * 272 + half * 128 + j * 16);
    f16* dst = Vt + ((long)(b * 8 + h) * 256 + fi) * 1024 + s0;
#pragma unroll
    for (int j = 0; j < 8; ++j) *(uint4*)(dst + j * 8) = q[j];
  }
}

// ---------------------------------------------------------------------------
// Fused attention v11: r7-exact formulas, but each wave covers 32 i-rows via
// TWO Q-fragment sets + acc sets that SHARE the same K and V LDS reads
// (K/V addresses are i-independent) -> LDS bytes per FLOP halved with only
// validated 16x16 formulas. Block = 4 waves x 32 i = 128 rows; grid 256.
// Counted-vmcnt 2-tile-ahead pipeline (r17 skeleton, equal-perf-validated).
// Epilogue: full-64KB swizzled bounce (r7 formula), 16-pass b128 stores.
// Zb aliases Qh. 256 threads.
// ---------------------------------------------------------------------------
__global__ __launch_bounds__(256) void attnk(
    const f16* __restrict__ Qh, const f16* __restrict__ Kh,
    const f16* __restrict__ Vt, f16* __restrict__ Zb) {
  __shared__ char sm[65536];  // 2 x (K 16KB + V 16KB); epilogue bounce reuses
  int flat = blockIdx.x;
  int xcd = flat & 7, slotb = flat >> 3;
  int bh = xcd + 8 * (slotb & 3);   // 4 heads per XCD -> K/V L2-resident
  int i0 = (slotb >> 2) * 128;      // 8 i-tiles of 128 rows
  int tid = threadIdx.x, wave = tid >> 6, lane = tid & 63;
  int l15 = lane & 15, l4 = lane >> 4;
  const f16* Qp = Qh + (long)bh * 262144;
  // q loads FIRST (oldest VMEM -> covered by the loop's vmcnt(8))
  f16x8 qA[8], qB[8];
  {
    const f16* qrA = Qp + (long)(i0 + wave * 32 + l15) * 256 + l4 * 8;
    const f16* qrB = qrA + 16 * 256;
#pragma unroll
    for (int t = 0; t < 8; ++t) qA[t] = *(const f16x8*)(qrA + t * 32);
#pragma unroll
    for (int t = 0; t < 8; ++t) qB[t] = *(const f16x8*)(qrB + t * 32);
  }
  f32x4 accA[16], accB[16];
#pragma unroll
  for (int n = 0; n < 16; ++n) {
    accA[n] = (f32x4){0.f, 0.f, 0.f, 0.f};
    accB[n] = (f32x4){0.f, 0.f, 0.f, 0.f};
  }

  // persistent per-lane global stage pointers (bytes)  (r7-exact)
  const char* kp[4];
  const char* vp[4];
  {
    const char* Kb = (const char*)(Kh + (long)bh * 262144);
    const char* Vb = (const char*)(Vt + (long)bh * 262144);
#pragma unroll
    for (int is = 0; is < 4; ++is) {
      int g = is * 4096 + wave * 1024 + lane * 16;
      int krow = g >> 9, ksl = (g >> 4) & 31;
      kp[is] = Kb + krow * 512 + ((ksl ^ krow) * 16);
      int f = g >> 6, jc = (g >> 4) & 3;
      vp[is] = Vb + f * 2048 + ((jc ^ ((f >> 1) & 3)) * 16);
    }
  }
  // XOR-composable LDS read bases (r7-exact; bb toggles bit 15)
  const int KB  = l15 * 512 + ((l4 * 16) ^ (l15 * 16));
  const int KB2 = KB + 8448;
  const int VB  = 16384 + l15 * 64 + ((l4 ^ ((l15 >> 1) & 3)) * 16);
  const int sdo = wave * 1024;

  auto STAGE = [&](int ob) {
#pragma unroll
    for (int is = 0; is < 4; ++is) {
      gload16(kp[is], sm + ob + is * 4096 + sdo);
      gload16(vp[is], sm + ob + 16384 + is * 4096 + sdo);
      kp[is] += 16384;
      vp[is] += 64;
    }
  };

  STAGE(0);      // tile 0 -> buf0
  STAGE(32768);  // tile 1 -> buf1
  int bb = 0;
  for (int jt = 0; jt < 32; ++jt) {
    if (jt < 31) asm volatile("s_waitcnt vmcnt(8)" ::: "memory");
    else         asm volatile("s_waitcnt vmcnt(0)" ::: "memory");
    __builtin_amdgcn_s_barrier();
    __builtin_amdgcn_sched_barrier(0);
    const int kb = KB ^ bb, kb2 = KB2 ^ bb, vb = VB ^ bb;
    // QK^T swapped, shared K reads feed both i-sets (4 indep chains)
    f32x4 sA0 = (f32x4){0.f, 0.f, 0.f, 0.f};
    f32x4 sA1 = (f32x4){0.f, 0.f, 0.f, 0.f};
    f32x4 sB0 = (f32x4){0.f, 0.f, 0.f, 0.f};
    f32x4 sB1 = (f32x4){0.f, 0.f, 0.f, 0.f};
    __builtin_amdgcn_s_setprio(1);
#pragma unroll
    for (int t = 0; t < 8; ++t) {
      f16x8 k0 = *(const f16x8*)(sm + (kb ^ (t * 64)));
      f16x8 k1 = *(const f16x8*)(sm + (kb2 ^ (t * 64)));
      sA0 = __builtin_amdgcn_mfma_f32_16x16x32_f16(k0, qA[t], sA0, 0, 0, 0);
      sB0 = __builtin_amdgcn_mfma_f32_16x16x32_f16(k0, qB[t], sB0, 0, 0, 0);
      sA1 = __builtin_amdgcn_mfma_f32_16x16x32_f16(k1, qA[t], sA1, 0, 0, 0);
      sB1 = __builtin_amdgcn_mfma_f32_16x16x32_f16(k1, qB[t], sB1, 0, 0, 0);
    }
    __builtin_amdgcn_s_setprio(0);
    // sigmoid + pack + permlane redistribution (r7-exact), per i-set
    f16x8 pavA, pavB;
    {
      unsigned u00 = __builtin_bit_cast(unsigned, __builtin_amdgcn_cvt_pkrtz(sgm(sA0[0]), sgm(sA0[1])));
      unsigned u01 = __builtin_bit_cast(unsigned, __builtin_amdgcn_cvt_pkrtz(sgm(sA0[2]), sgm(sA0[3])));
      unsigned u10 = __builtin_bit_cast(unsigned, __builtin_amdgcn_cvt_pkrtz(sgm(sA1[0]), sgm(sA1[1])));
      unsigned u11 = __builtin_bit_cast(unsigned, __builtin_amdgcn_cvt_pkrtz(sgm(sA1[2]), sgm(sA1[3])));
      auto a0 = __builtin_amdgcn_permlane32_swap(u00, u10, false, false);
      auto w02 = __builtin_amdgcn_permlane16_swap(a0[0], a0[1], false, false);
      auto a1 = __builtin_amdgcn_permlane32_swap(u01, u11, false, false);
      auto w13 = __builtin_amdgcn_permlane16_swap(a1[0], a1[1], false, false);
      u32x4 paw;
      paw[0] = w02[0]; paw[1] = w13[0]; paw[2] = w02[1]; paw[3] = w13[1];
      pavA = __builtin_bit_cast(f16x8, paw);
    }
    {
      unsigned u00 = __builtin_bit_cast(unsigned, __builtin_amdgcn_cvt_pkrtz(sgm(sB0[0]), sgm(sB0[1])));
      unsigned u01 = __builtin_bit_cast(unsigned, __builtin_amdgcn_cvt_pkrtz(sgm(sB0[2]), sgm(sB0[3])));
      unsigned u10 = __builtin_bit_cast(unsigned, __builtin_amdgcn_cvt_pkrtz(sgm(sB1[0]), sgm(sB1[1])));
      unsigned u11 = __builtin_bit_cast(unsigned, __builtin_amdgcn_cvt_pkrtz(sgm(sB1[2]), sgm(sB1[3])));
      auto a0 = __builtin_amdgcn_permlane32_swap(u00, u10, false, false);
      auto w02 = __builtin_amdgcn_permlane16_swap(a0[0], a0[1], false, false);
      auto a1 = __builtin_amdgcn_permlane32_swap(u01, u11, false, false);
      auto w13 = __builtin_amdgcn_permlane16_swap(a1[0], a1[1], false, false);
      u32x4 paw;
      paw[0] = w02[0]; paw[1] = w13[0]; paw[2] = w02[1]; paw[3] = w13[1];
      pavB = __builtin_bit_cast(f16x8, paw);
    }
    // PV: shared V reads feed both i-sets
    __builtin_amdgcn_s_setprio(1);
#pragma unroll
    for (int n = 0; n < 16; ++n) {
      f16x8 vbf = *(const f16x8*)(sm + (vb ^ (n * 1024)));
      accA[n] = __builtin_amdgcn_mfma_f32_16x16x32_f16(pavA, vbf, accA[n], 0, 0, 0);
      accB[n] = __builtin_amdgcn_mfma_f32_16x16x32_f16(pavB, vbf, accB[n], 0, 0, 0);
    }
    __builtin_amdgcn_s_setprio(0);
    __builtin_amdgcn_sched_barrier(0);
    asm volatile("s_waitcnt lgkmcnt(0)" ::: "memory");
    __builtin_amdgcn_s_barrier();   // all waves done reading buf bb
    __builtin_amdgcn_sched_barrier(0);
    if (jt < 30) STAGE(bb);         // tile jt+2 overwrites buf bb
    bb ^= 32768;
  }
  // epilogue: bounce 128x256 f16 through swizzled LDS (64KB), b128 stores
#pragma unroll
  for (int nf = 0; nf < 16; ++nf)
#pragma unroll
    for (int r = 0; r < 4; ++r) {
      int ilA = wave * 32 + l4 * 4 + r;
      int ilB = ilA + 16;
      int f = nf * 16 + l15;
      *(f16*)(sm + ilA * 512 + ((f * 2) ^ (((ilA >> 2) & 3) << 5))) = (f16)accA[nf][r];
      *(f16*)(sm + ilB * 512 + ((f * 2) ^ (((ilB >> 2) & 3) << 5))) = (f16)accB[nf][r];
    }
  __syncthreads();
  f16* zp = Zb + ((long)bh * 1024 + i0) * 256;
#pragma unroll
  for (int c = 0; c < 16; ++c) {
    int il = c * 8 + (tid >> 5);
    int fb = (tid & 31) * 16;
    uint4 v = *(const uint4*)(sm + il * 512 + (fb ^ (((il >> 2) & 3) << 5)));
    *(uint4*)((char*)zp + il * 512 + fb) = v;
  }
}

// ---------------------------------------------------------------------------
// Output projection + ReLU, double-buffered, BK=128 (r11-exact, validated).
// grid (4,16,4), 256 threads.
// ---------------------------------------------------------------------------
__global__ __launch_bounds__(256) void zkern(
    const f16* __restrict__ Wzt, const f16* __restrict__ Zb,
    float* __restrict__ out) {
  __shared__ char sm[65536];  // 2 x (16KB A + 16KB B)
  int fo0 = blockIdx.x * 64, s0 = blockIdx.y * 64, b = blockIdx.z;
  int tid = threadIdx.x, wave = tid >> 6, lane = tid & 63;
  int wm = wave & 1, wn = wave >> 1;
  f32x4 acc[2][2];
#pragma unroll
  for (int i = 0; i < 2; ++i)
#pragma unroll
    for (int j = 0; j < 2; ++j) acc[i][j] = (f32x4){0.f, 0.f, 0.f, 0.f};

  auto ZSTAGE = [&](int buf, int kt) {
    char* As = sm + buf * 32768;
    char* Bs = As + 16384;
    int k0 = kt * 128, h = k0 >> 8, fi0 = k0 & 255;
#pragma unroll
    for (int is = 0; is < 4; ++is) {
      int loff = is * 4096 + wave * 1024;
      int g = loff + lane * 16;
      int row = g >> 8, sl = (g >> 4) & 15;
      int sp = (sl ^ (row & 15)) * 8;
      gload16(Wzt + (long)(fo0 + row) * 2048 + k0 + sp, As + loff);
      gload16(Zb + ((long)(b * 8 + h) * 1024 + s0 + row) * 256 + fi0 + sp, Bs + loff);
    }
  };

  ZSTAGE(0, 0);
  __syncthreads();
  for (int kt = 0; kt < 16; ++kt) {
    int cur = kt & 1;
    if (kt < 15) ZSTAGE(cur ^ 1, kt + 1);
    const char* As = sm + cur * 32768;
    const char* Bs = As + 16384;
#pragma unroll
    for (int t = 0; t < 4; ++t) {
      f16x8 af[2], bf[2];
#pragma unroll
      for (int mi = 0; mi < 2; ++mi) {
        int row = wm * 32 + mi * 16 + (lane & 15);
        int sl = (t * 4 + (lane >> 4)) ^ (row & 15);
        af[mi] = *(const f16x8*)(As + row * 256 + sl * 16);
      }
#pragma unroll
      for (int ni = 0; ni < 2; ++ni) {
        int row = wn * 32 + ni * 16 + (lane & 15);
        int sl = (t * 4 + (lane >> 4)) ^ (row & 15);
        bf[ni] = *(const f16x8*)(Bs + row * 256 + sl * 16);
      }
#pragma unroll
      for (int mi = 0; mi < 2; ++mi)
#pragma unroll
        for (int ni = 0; ni < 2; ++ni)
          acc[mi][ni] = __builtin_amdgcn_mfma_f32_16x16x32_f16(af[mi], bf[ni], acc[mi][ni], 0, 0, 0);
    }
    __syncthreads();
  }
#pragma unroll
  for (int mi = 0; mi < 2; ++mi)
#pragma unroll
    for (int ni = 0; ni < 2; ++ni)
#pragma unroll
      for (int r = 0; r < 4; ++r) {
        int fo = fo0 + wm * 32 + mi * 16 + (lane >> 4) * 4 + r;
        int s = s0 + wn * 32 + ni * 16 + (lane & 15);
        float v = acc[mi][ni][r];
        out[((long)b * 256 + fo) * 1024 + s] = v > 0.f ? v : 0.f;
      }
}

extern "C" void kernel_launch(void* const* d_in, const int* in_sizes, int n_in,
                              void* d_out, int out_size, void* d_ws, size_t ws_size,
                              hipStream_t stream) {
  const float* qin = (const float*)d_in[0];
  const float* kvin = (const float*)d_in[1];
  const float* Wq = (const float*)d_in[2];
  const float* Wk = (const float*)d_in[3];
  const float* Wv = (const float*)d_in[4];
  const float* Wz = (const float*)d_in[5];
  float* out = (float*)d_out;
  char* ws = (char*)d_ws;
  const long MB = 1 << 20;
  f16* Xq  = (f16*)(ws + 0 * MB);
  f16* Xkv = (f16*)(ws + 2 * MB);
  f16* Wqt = (f16*)(ws + 4 * MB);
  f16* Wkt = (f16*)(ws + 5 * MB);
  f16* Wvt = (f16*)(ws + 6 * MB);
  f16* Wzt = (f16*)(ws + 7 * MB);
  f16* Qh  = (f16*)(ws + 8 * MB);   // 16MB, aliased by Zb
  f16* Kh  = (f16*)(ws + 24 * MB);  // 16MB
  f16* Vt  = (f16*)(ws + 40 * MB);  // 16MB
  f16* Zb  = Qh;
  dim3 blk(256);
  tall<<<dim3(1024), blk, 0, stream>>>(qin, kvin, Wq, Wk, Wv, Wz,
                                       Xq, Xkv, Wqt, Wkt, Wvt, Wzt);
  projk<<<dim3(32, 16, 3), blk, 0, stream>>>(Xq, Xkv, Wqt, Wkt, Wvt, Qh, Kh, Vt);
  attnk<<<dim3(256), blk, 0, stream>>>(Qh, Kh, Vt, Zb);
  zkern<<<dim3(4, 16, 4), blk, 0, stream>>>(Wzt, Zb, out);
}

// Round 19
// 112.214 us; speedup vs baseline: 1.1027x; 1.1027x over previous
//
#include <hip/hip_runtime.h>
#include <hip/hip_fp16.h>

typedef _Float16 f16;
typedef _Float16 f16x8 __attribute__((ext_vector_type(8)));
typedef float f32x4 __attribute__((ext_vector_type(4)));
typedef unsigned u32x4 __attribute__((ext_vector_type(4)));

#define AS1(p) ((const __attribute__((address_space(1))) void*)(p))
#define AS3(p) ((__attribute__((address_space(3))) void*)(p))

__device__ __forceinline__ void gload16(const void* g, void* l) {
  __builtin_amdgcn_global_load_lds(AS1(g), AS3(l), 16, 0, 0);
}

__device__ __forceinline__ float sgm(float x) {
  // sigmoid(16*x) = 1/(1+2^(-16*log2e*x))
  return __builtin_amdgcn_rcpf(1.0f + __builtin_amdgcn_exp2f(x * -23.083120654223414f));
}

// ---------------------------------------------------------------------------
// Tiled transpose + f32->f16 convert body: 64x64 tile.
// ---------------------------------------------------------------------------
__device__ __forceinline__ void tbody(const float* __restrict__ ip,
                                      f16* __restrict__ op,
                                      long in_rs, long out_rs) {
  __shared__ float t[64][68];
  int tid = threadIdx.x;
  {
    int c4 = (tid & 15) * 4, r0 = tid >> 4;
#pragma unroll
    for (int p = 0; p < 4; ++p) {
      int r = r0 + 16 * p;
      float4 v = *(const float4*)(ip + (long)r * in_rs + c4);
      t[c4 + 0][r] = v.x; t[c4 + 1][r] = v.y; t[c4 + 2][r] = v.z; t[c4 + 3][r] = v.w;
    }
  }
  __syncthreads();
  {
    int r4 = (tid & 15) * 4, c0 = tid >> 4;
#pragma unroll
    for (int p = 0; p < 4; ++p) {
      int c = c0 + 16 * p;
      float4 v = *(const float4*)(&t[c][r4]);
      union { f16 h[4]; unsigned long long u; } pk;
      pk.h[0] = (f16)v.x; pk.h[1] = (f16)v.y; pk.h[2] = (f16)v.z; pk.h[3] = (f16)v.w;
      *(unsigned long long*)(op + (long)c * out_rs + r4) = pk.u;
    }
  }
}

// All input transposes in one launch. Flat grid 1024 blocks.
__global__ __launch_bounds__(256) void tall(
    const float* __restrict__ qin, const float* __restrict__ kvin,
    const float* __restrict__ Wq, const float* __restrict__ Wk,
    const float* __restrict__ Wv, const float* __restrict__ Wz,
    f16* __restrict__ Xq, f16* __restrict__ Xkv,
    f16* __restrict__ Wqt, f16* __restrict__ Wkt, f16* __restrict__ Wvt,
    f16* __restrict__ Wzt) {
  int id = blockIdx.x;
  if (id < 512) {
    int x = id & 15, y = (id >> 4) & 3, z = id >> 6;
    const float* in = (z < 4) ? qin : kvin;
    f16* out = (z < 4) ? Xq : Xkv;
    long b = z & 3;
    tbody(in + b * 262144 + (long)(y * 64) * 1024 + x * 64,
          out + b * 262144 + (long)(x * 64) * 256 + y * 64, 1024, 256);
  } else if (id < 896) {
    int t = id - 512;
    int x = t & 31, y = (t >> 5) & 3, z = t >> 7;
    const float* in = (z == 0) ? Wq : (z == 1) ? Wk : Wv;
    f16* out = (z == 0) ? Wqt : (z == 1) ? Wkt : Wvt;
    tbody(in + (long)(y * 64) * 2048 + x * 64,
          out + (long)(x * 64) * 256 + y * 64, 2048, 256);
  } else {
    int t = id - 896;
    int x = t & 3, y = (t >> 2) & 3;
    long z = t >> 4;
    tbody(Wz + z * 256 + (long)(y * 64) * 2048 + x * 64,
          Wzt + z * 256 + (long)(x * 64) * 2048 + y * 64, 2048, 2048);
  }
}

// ---------------------------------------------------------------------------
// QKV projection v3: BK=32 for occupancy + pipeline depth. Buffers
// (8KB A + 8KB B), dbuf 32KB -> 4 resident blocks/CU (16 waves) and 8 kt
// iterations (vs 2 blocks / 4 iters at BK=64). Swizzle: slot = chunk^(row&3)
// (r7 family scaled to 4 slots; 2-way banks both sides, involution).
// Epilogue r11-exact. z=0: Q -> Qh; z=1: K -> Kh; z=2: V -> Vt.
// grid (32,16,3), 256 threads.
// ---------------------------------------------------------------------------
__global__ __launch_bounds__(256) void projk(
    const f16* __restrict__ Xq, const f16* __restrict__ Xkv,
    const f16* __restrict__ Wqt, const f16* __restrict__ Wkt, const f16* __restrict__ Wvt,
    f16* __restrict__ Qh, f16* __restrict__ Kh, f16* __restrict__ Vt) {
  __shared__ char sm[36864];  // 2 x (8KB A + 8KB B) dbuf; 34.8KB epilogue bounce
  int z = blockIdx.z;
  const f16* A = (z == 0) ? Xq : Xkv;
  const f16* B = (z == 0) ? Wqt : (z == 1) ? Wkt : Wvt;
  int m0 = blockIdx.x * 128, n0 = blockIdx.y * 128;
  int tid = threadIdx.x, wave = tid >> 6, lane = tid & 63;
  int wm = wave & 1, wn = wave >> 1;
  int l15 = lane & 15, l4 = lane >> 4;
  f32x4 acc[4][4];
#pragma unroll
  for (int i = 0; i < 4; ++i)
#pragma unroll
    for (int j = 0; j < 4; ++j) acc[i][j] = (f32x4){0.f, 0.f, 0.f, 0.f};

  auto PSTAGE = [&](int buf, int kt) {
    char* As = sm + buf * 16384;
    char* Bs = As + 8192;
    int k0 = kt * 32;
#pragma unroll
    for (int is = 0; is < 2; ++is) {
      int o = is * 4096 + tid * 16;
      int row = o >> 6, sl = (o >> 4) & 3;
      int sp = (sl ^ (row & 3)) * 8;
      gload16(A + (long)(m0 + row) * 256 + k0 + sp, As + o);
      gload16(B + (long)(n0 + row) * 256 + k0 + sp, Bs + o);
    }
  };

  PSTAGE(0, 0);
  __syncthreads();
  for (int kt = 0; kt < 8; ++kt) {
    int cur = kt & 1;
    if (kt < 7) PSTAGE(cur ^ 1, kt + 1);
    const char* As = sm + cur * 16384;
    const char* Bs = As + 8192;
    f16x8 af[4], bf[4];
#pragma unroll
    for (int mi = 0; mi < 4; ++mi) {
      int row = wm * 64 + mi * 16 + l15;
      int sl = l4 ^ (row & 3);
      af[mi] = *(const f16x8*)(As + row * 64 + sl * 16);
    }
#pragma unroll
    for (int ni = 0; ni < 4; ++ni) {
      int row = wn * 64 + ni * 16 + l15;
      int sl = l4 ^ (row & 3);
      bf[ni] = *(const f16x8*)(Bs + row * 64 + sl * 16);
    }
#pragma unroll
    for (int mi = 0; mi < 4; ++mi)
#pragma unroll
      for (int ni = 0; ni < 4; ++ni)
        acc[mi][ni] = __builtin_amdgcn_mfma_f32_16x16x32_f16(af[mi], bf[ni], acc[mi][ni], 0, 0, 0);
    __syncthreads();
  }
  // bounce tile into LDS as L[cc][rs], row stride 272B (r11-exact)
#pragma unroll
  for (int mi = 0; mi < 4; ++mi)
#pragma unroll
    for (int ni = 0; ni < 4; ++ni) {
      int cc = wn * 64 + ni * 16 + l15;
      int rs0 = wm * 64 + mi * 16 + l4 * 4;
      union { f16 h[4]; unsigned long long u; } pk;
#pragma unroll
      for (int r = 0; r < 4; ++r) pk.h[r] = (f16)acc[mi][ni][r];
      *(unsigned long long*)(sm + cc * 272 + rs0 * 2) = pk.u;
    }
  __syncthreads();
  if (z < 2) {
    f16* outp = (z == 0) ? Qh : Kh;
#pragma unroll
    for (int pass = 0; pass < 4; ++pass) {
      int item = pass * 256 + tid;
      int rs = item & 127, h = item >> 7;
      int m = m0 + rs, b = m >> 10, s = m & 1023;
      union { unsigned short u16[16]; uint4 q[2]; } pk;
#pragma unroll
      for (int u = 0; u < 16; ++u)
        pk.u16[u] = *(const unsigned short*)(sm + (h + 8 * u) * 272 + rs * 2);
      f16* dst = outp + ((long)(b * 8 + h) * 1024 + s) * 256 + (n0 >> 3);
      *(uint4*)dst = pk.q[0];
      *(uint4*)(dst + 8) = pk.q[1];
    }
  } else {
    int cc = tid >> 1, half = tid & 1;
    int c = n0 + cc, h = c & 7, fi = c >> 3;
    int m = m0 + half * 64;
    int b = m >> 10, s0 = m & 1023;
    uint4 q[8];
#pragma unroll
    for (int j = 0; j < 8; ++j)
      q[j] = *(const uint4*)(sm + cc * 272 + half * 128 + j * 16);
    f16* dst = Vt + ((long)(b * 8 + h) * 256 + fi) * 1024 + s0;
#pragma unroll
    for (int j = 0; j < 8; ++j) *(uint4*)(dst + j * 8) = q[j];
  }
}

// ---------------------------------------------------------------------------
// Fused attention (r17-exact, validated 57.4us): r7 formulas + counted-vmcnt
// 2-tile-ahead pipeline. Zb aliases Qh. grid 512, 256 threads.
// ---------------------------------------------------------------------------
__global__ __launch_bounds__(256) void attnk(
    const f16* __restrict__ Qh, const f16* __restrict__ Kh,
    const f16* __restrict__ Vt, f16* __restrict__ Zb) {
  __shared__ char sm[65536];  // 2 x (K 16KB + V 16KB); epilogue bounce reuses
  int flat = blockIdx.x;
  int xcd = flat & 7, slotb = flat >> 3;
  int bh = xcd + 8 * (slotb & 3);   // 4 heads per XCD -> K/V L2-resident
  int i0 = (slotb >> 2) * 64;
  int tid = threadIdx.x, wave = tid >> 6, lane = tid & 63;
  int l15 = lane & 15, l4 = lane >> 4;
  const f16* Qp = Qh + (long)bh * 262144;
  // q loads FIRST (oldest VMEM -> covered by the loop's vmcnt(8))
  f16x8 q[8];
  {
    const f16* qr = Qp + (long)(i0 + wave * 16 + l15) * 256 + l4 * 8;
#pragma unroll
    for (int t = 0; t < 8; ++t) q[t] = *(const f16x8*)(qr + t * 32);
  }
  f32x4 acc[16];
#pragma unroll
  for (int n = 0; n < 16; ++n) acc[n] = (f32x4){0.f, 0.f, 0.f, 0.f};

  // persistent per-lane global stage pointers (bytes)
  const char* kp[4];
  const char* vp[4];
  {
    const char* Kb = (const char*)(Kh + (long)bh * 262144);
    const char* Vb = (const char*)(Vt + (long)bh * 262144);
#pragma unroll
    for (int is = 0; is < 4; ++is) {
      int g = is * 4096 + wave * 1024 + lane * 16;
      int krow = g >> 9, ksl = (g >> 4) & 31;
      kp[is] = Kb + krow * 512 + ((ksl ^ krow) * 16);
      int f = g >> 6, jc = (g >> 4) & 3;
      vp[is] = Vb + f * 2048 + ((jc ^ ((f >> 1) & 3)) * 16);
    }
  }
  // XOR-composable LDS read bases (byte offsets; bb toggles bit 15)
  const int KB  = l15 * 512 + ((l4 * 16) ^ (l15 * 16));
  const int KB2 = KB + 8448;  // +8192 (16 rows) +256 (chunk^16)
  const int VB  = 16384 + l15 * 64 + ((l4 ^ ((l15 >> 1) & 3)) * 16);
  const int sdo = wave * 1024;  // wave-uniform stage dest base

  auto STAGE = [&](int ob) {
#pragma unroll
    for (int is = 0; is < 4; ++is) {
      gload16(kp[is], sm + ob + is * 4096 + sdo);
      gload16(vp[is], sm + ob + 16384 + is * 4096 + sdo);
      kp[is] += 16384;
      vp[is] += 64;
    }
  };

  STAGE(0);      // tile 0 -> buf0 (8 loads in flight)
  STAGE(32768);  // tile 1 -> buf1 (16 in flight)
  int bb = 0;
  for (int jt = 0; jt < 32; ++jt) {
    if (jt < 31) asm volatile("s_waitcnt vmcnt(8)" ::: "memory");
    else         asm volatile("s_waitcnt vmcnt(0)" ::: "memory");
    __builtin_amdgcn_s_barrier();
    __builtin_amdgcn_sched_barrier(0);
    const int kb = KB ^ bb, kb2 = KB2 ^ bb, vb = VB ^ bb;
    // QK^T swapped: A=K rows j, B=Q cols i -> lane holds S[i=l15][8 j's]
    f32x4 s0 = (f32x4){0.f, 0.f, 0.f, 0.f};
    f32x4 s1 = (f32x4){0.f, 0.f, 0.f, 0.f};
    __builtin_amdgcn_s_setprio(1);
#pragma unroll
    for (int t = 0; t < 8; ++t) {
      f16x8 k0 = *(const f16x8*)(sm + (kb ^ (t * 64)));
      f16x8 k1 = *(const f16x8*)(sm + (kb2 ^ (t * 64)));
      s0 = __builtin_amdgcn_mfma_f32_16x16x32_f16(k0, q[t], s0, 0, 0, 0);
      s1 = __builtin_amdgcn_mfma_f32_16x16x32_f16(k1, q[t], s1, 0, 0, 0);
    }
    __builtin_amdgcn_s_setprio(0);
    // sigmoid + pack pairs (cvt_pkrtz): lane holds P[i=l15][j]
    unsigned u00 = __builtin_bit_cast(unsigned, __builtin_amdgcn_cvt_pkrtz(sgm(s0[0]), sgm(s0[1])));
    unsigned u01 = __builtin_bit_cast(unsigned, __builtin_amdgcn_cvt_pkrtz(sgm(s0[2]), sgm(s0[3])));
    unsigned u10 = __builtin_bit_cast(unsigned, __builtin_amdgcn_cvt_pkrtz(sgm(s1[0]), sgm(s1[1])));
    unsigned u11 = __builtin_bit_cast(unsigned, __builtin_amdgcn_cvt_pkrtz(sgm(s1[2]), sgm(s1[3])));
    // redistribute to PV A-frag (validated r3/r4 mapping)
    auto a0 = __builtin_amdgcn_permlane32_swap(u00, u10, false, false);
    auto w02 = __builtin_amdgcn_permlane16_swap(a0[0], a0[1], false, false);
    auto a1 = __builtin_amdgcn_permlane32_swap(u01, u11, false, false);
    auto w13 = __builtin_amdgcn_permlane16_swap(a1[0], a1[1], false, false);
    u32x4 paw;
    paw[0] = w02[0]; paw[1] = w13[0]; paw[2] = w02[1]; paw[3] = w13[1];
    f16x8 pav = __builtin_bit_cast(f16x8, paw);
    // PV: wave covers its 16 i-rows x all 256 f
    __builtin_amdgcn_s_setprio(1);
#pragma unroll
    for (int n = 0; n < 16; ++n) {
      f16x8 vbf = *(const f16x8*)(sm + (vb ^ (n * 1024)));
      acc[n] = __builtin_amdgcn_mfma_f32_16x16x32_f16(pav, vbf, acc[n], 0, 0, 0);
    }
    __builtin_amdgcn_s_setprio(0);
    __builtin_amdgcn_sched_barrier(0);
    asm volatile("s_waitcnt lgkmcnt(0)" ::: "memory");
    __builtin_amdgcn_s_barrier();   // all waves done reading buf bb
    __builtin_amdgcn_sched_barrier(0);
    if (jt < 30) STAGE(bb);         // tile jt+2 overwrites buf bb
    bb ^= 32768;
  }
  // epilogue: bounce 64x256 f16 through swizzled LDS, coalesced b128 stores
#pragma unroll
  for (int nf = 0; nf < 16; ++nf)
#pragma unroll
    for (int r = 0; r < 4; ++r) {
      int il = wave * 16 + l4 * 4 + r;
      int f = nf * 16 + l15;
      *(f16*)(sm + il * 512 + ((f * 2) ^ (((il >> 2) & 3) << 5))) = (f16)acc[nf][r];
    }
  __syncthreads();
  f16* zp = Zb + ((long)bh * 1024 + i0) * 256;
#pragma unroll
  for (int c = 0; c < 8; ++c) {
    int il = c * 8 + (tid >> 5);
    int fb = (tid & 31) * 16;
    uint4 v = *(const uint4*)(sm + il * 512 + (fb ^ (((il >> 2) & 3) << 5)));
    *(uint4*)((char*)zp + il * 512 + fb) = v;
  }
}

// ---------------------------------------------------------------------------
// Output projection + ReLU, double-buffered, BK=128 (r11-exact, validated).
// grid (4,16,4), 256 threads.
// ---------------------------------------------------------------------------
__global__ __launch_bounds__(256) void zkern(
    const f16* __restrict__ Wzt, const f16* __restrict__ Zb,
    float* __restrict__ out) {
  __shared__ char sm[65536];  // 2 x (16KB A + 16KB B)
  int fo0 = blockIdx.x * 64, s0 = blockIdx.y * 64, b = blockIdx.z;
  int tid = threadIdx.x, wave = tid >> 6, lane = tid & 63;
  int wm = wave & 1, wn = wave >> 1;
  f32x4 acc[2][2];
#pragma unroll
  for (int i = 0; i < 2; ++i)
#pragma unroll
    for (int j = 0; j < 2; ++j) acc[i][j] = (f32x4){0.f, 0.f, 0.f, 0.f};

  auto ZSTAGE = [&](int buf, int kt) {
    char* As = sm + buf * 32768;
    char* Bs = As + 16384;
    int k0 = kt * 128, h = k0 >> 8, fi0 = k0 & 255;
#pragma unroll
    for (int is = 0; is < 4; ++is) {
      int loff = is * 4096 + wave * 1024;
      int g = loff + lane * 16;
      int row = g >> 8, sl = (g >> 4) & 15;
      int sp = (sl ^ (row & 15)) * 8;
      gload16(Wzt + (long)(fo0 + row) * 2048 + k0 + sp, As + loff);
      gload16(Zb + ((long)(b * 8 + h) * 1024 + s0 + row) * 256 + fi0 + sp, Bs + loff);
    }
  };

  ZSTAGE(0, 0);
  __syncthreads();
  for (int kt = 0; kt < 16; ++kt) {
    int cur = kt & 1;
    if (kt < 15) ZSTAGE(cur ^ 1, kt + 1);
    const char* As = sm + cur * 32768;
    const char* Bs = As + 16384;
#pragma unroll
    for (int t = 0; t < 4; ++t) {
      f16x8 af[2], bf[2];
#pragma unroll
      for (int mi = 0; mi < 2; ++mi) {
        int row = wm * 32 + mi * 16 + (lane & 15);
        int sl = (t * 4 + (lane >> 4)) ^ (row & 15);
        af[mi] = *(const f16x8*)(As + row * 256 + sl * 16);
      }
#pragma unroll
      for (int ni = 0; ni < 2; ++ni) {
        int row = wn * 32 + ni * 16 + (lane & 15);
        int sl = (t * 4 + (lane >> 4)) ^ (row & 15);
        bf[ni] = *(const f16x8*)(Bs + row * 256 + sl * 16);
      }
#pragma unroll
      for (int mi = 0; mi < 2; ++mi)
#pragma unroll
        for (int ni = 0; ni < 2; ++ni)
          acc[mi][ni] = __builtin_amdgcn_mfma_f32_16x16x32_f16(af[mi], bf[ni], acc[mi][ni], 0, 0, 0);
    }
    __syncthreads();
  }
#pragma unroll
  for (int mi = 0; mi < 2; ++mi)
#pragma unroll
    for (int ni = 0; ni < 2; ++ni)
#pragma unroll
      for (int r = 0; r < 4; ++r) {
        int fo = fo0 + wm * 32 + mi * 16 + (lane >> 4) * 4 + r;
        int s = s0 + wn * 32 + ni * 16 + (lane & 15);
        float v = acc[mi][ni][r];
        out[((long)b * 256 + fo) * 1024 + s] = v > 0.f ? v : 0.f;
      }
}

extern "C" void kernel_launch(void* const* d_in, const int* in_sizes, int n_in,
                              void* d_out, int out_size, void* d_ws, size_t ws_size,
                              hipStream_t stream) {
  const float* qin = (const float*)d_in[0];
  const float* kvin = (const float*)d_in[1];
  const float* Wq = (const float*)d_in[2];
  const float* Wk = (const float*)d_in[3];
  const float* Wv = (const float*)d_in[4];
  const float* Wz = (const float*)d_in[5];
  float* out = (float*)d_out;
  char* ws = (char*)d_ws;
  const long MB = 1 << 20;
  f16* Xq  = (f16*)(ws + 0 * MB);
  f16* Xkv = (f16*)(ws + 2 * MB);
  f16* Wqt = (f16*)(ws + 4 * MB);
  f16* Wkt = (f16*)(ws + 5 * MB);
  f16* Wvt = (f16*)(ws + 6 * MB);
  f16* Wzt = (f16*)(ws + 7 * MB);
  f16* Qh  = (f16*)(ws + 8 * MB);   // 16MB, aliased by Zb
  f16* Kh  = (f16*)(ws + 24 * MB);  // 16MB
  f16* Vt  = (f16*)(ws + 40 * MB);  // 16MB
  f16* Zb  = Qh;
  dim3 blk(256);
  tall<<<dim3(1024), blk, 0, stream>>>(qin, kvin, Wq, Wk, Wv, Wz,
                                       Xq, Xkv, Wqt, Wkt, Wvt, Wzt);
  projk<<<dim3(32, 16, 3), blk, 0, stream>>>(Xq, Xkv, Wqt, Wkt, Wvt, Qh, Kh, Vt);
  attnk<<<dim3(512), blk, 0, stream>>>(Qh, Kh, Vt, Zb);
  zkern<<<dim3(4, 16, 4), blk, 0, stream>>>(Wzt, Zb, out);
}